// Round 1
// baseline (1188.501 us; speedup 1.0000x reference)
//
#include <hip/hip_runtime.h>

// ---------------------------------------------------------------------------
// Grid attention, fused per-window kernel, bf16 MFMA (gfx950).
//   B=4, X=Y=32 -> 4096 windows; n=49 tokens; D=512; 16 heads x 32.
// ws layout:
//   [0, 512KB)        Wq  pre-swizzled B-frags  [h][nt][ks][lane][8] bf16 (scale folded)
//   [512KB, 1MB)      Wk  same
//   [1MB, 1.5MB)      Wv  same
//   [1.5MB, 2.5MB)    biasD [h][mt][nt][lane][4] f32 (D-layout; -1e30 for j>=49)
// Requires ws_size >= 2,621,440 bytes.
// ---------------------------------------------------------------------------

typedef __bf16 bf16x8 __attribute__((ext_vector_type(8)));
typedef __attribute__((ext_vector_type(8))) short short8;
typedef __attribute__((ext_vector_type(4))) float f32x4;

#define DEVI __device__ __forceinline__

DEVI unsigned short f2bf(float f) {
  union { float f; unsigned u; } v; v.f = f;
  unsigned r = v.u + 0x7FFFu + ((v.u >> 16) & 1u);
  return (unsigned short)(r >> 16);
}

DEVI bf16x8 bf_zero() {
  short8 z = {0, 0, 0, 0, 0, 0, 0, 0};
  return __builtin_bit_cast(bf16x8, z);
}

#define MFMA16(a, b, c) __builtin_amdgcn_mfma_f32_16x16x32_bf16((a), (b), (c), 0, 0, 0)

// ---------------- prep: weights -> swizzled bf16 frags, bias -> D-layout ----
__global__ void prep_kernel(const float* __restrict__ Wq, const float* __restrict__ Wkv,
                            const float* __restrict__ bt, char* __restrict__ ws) {
  int t = blockIdx.x * 256 + threadIdx.x;
  if (t < 786432) {  // 3 * 16 * 2 * 16 * 64 * 8 bf16 elements
    int e = t & 7, lane = (t >> 3) & 63, ks = (t >> 9) & 15, nt = (t >> 13) & 1,
        h = (t >> 14) & 15, T = t >> 18;
    int row = ks * 32 + (lane >> 4) * 8 + e;     // K index in [0,512)
    int col = h * 32 + nt * 16 + (lane & 15);    // N index
    float v;
    if (T == 0)      v = Wq[row * 512 + col] * 0.17677669529663687f;  // fold 1/sqrt(32)
    else if (T == 1) v = Wkv[row * 1024 + col];
    else             v = Wkv[row * 1024 + 512 + col];
    ((unsigned short*)ws)[t] = f2bf(v);
  }
  if (t < 262144) {  // 16 * 4 * 4 * 64 * 4 f32
    int r = t & 3, lane = (t >> 2) & 63, nt = (t >> 8) & 3, mt = (t >> 10) & 3,
        h = (t >> 12) & 15;
    int i = mt * 16 + (lane >> 4) * 4 + r;
    int j = nt * 16 + (lane & 15);
    float v;
    if (j >= 49)      v = -1e30f;   // mask padded key columns
    else if (i >= 49) v = 0.0f;     // padded query rows: value irrelevant, keep finite
    else {
      int hi = i / 7, wi = i % 7, hj = j / 7, wj = j % 7;
      v = bt[((hi - hj + 6) * 13 + (wi - wj + 6)) * 16 + h];
    }
    ((float*)(ws + 1572864))[t] = v;
  }
}

// ---------------- LDS fragment loaders (all XOR-swizzled) -------------------
// xb/yb: [49][512] bf16, row stride 1024B, swz bits 4-6
DEVI bf16x8 ldXY(const char* base, int row, int kc) {
  unsigned a = ((unsigned)(row * 1024 + kc * 2)) ^ (((unsigned)row & 7u) << 4);
  return *(const bf16x8*)(base + a);
}
DEVI bf16x8 ldXY_c(const char* base, int row, int kc) {
  int rc = row < 48 ? row : 48;
  bf16x8 v = ldXY(base, rc, kc);
  if (row > 48) v = bf_zero();
  return v;
}
// qb/kb: [49][32] bf16, row stride 64B, swz bits 4-5
DEVI bf16x8 ldQK(const char* base, int row, int kc) {
  int rc = row < 48 ? row : 48;
  unsigned a = ((unsigned)(rc * 64 + kc * 2)) ^ (((unsigned)rc & 3u) << 4);
  bf16x8 v = *(const bf16x8*)(base + a);
  if (row > 48) v = bf_zero();
  return v;
}
// pb: [49][64] bf16, row stride 128B, swz bits 4-6
DEVI bf16x8 ldP(const char* base, int row, int kc) {
  int rc = row < 48 ? row : 48;
  unsigned a = ((unsigned)(rc * 128 + kc * 2)) ^ (((unsigned)rc & 7u) << 4);
  bf16x8 v = *(const bf16x8*)(base + a);
  if (row > 48) v = bf_zero();
  return v;
}
// vt: [32][64] bf16 (V transposed: [dh][j]), row stride 128B, swz bits 4-6
DEVI bf16x8 ldVT(const char* base, int dh, int kc) {
  unsigned a = ((unsigned)(dh * 128 + kc * 2)) ^ (((unsigned)dh & 7u) << 4);
  return *(const bf16x8*)(base + a);
}

// ---------------- main fused kernel ----------------------------------------
__global__ __launch_bounds__(256, 1)
void attn_kernel(const float* __restrict__ x, const float* __restrict__ y,
                 const char* __restrict__ wsW, const float* __restrict__ biasD,
                 float* __restrict__ out) {
  extern __shared__ char smem[];
  char* xb = smem;            // 50176
  char* yb = smem + 50176;    // 50176
  const int tid = threadIdx.x;
  const int lane = tid & 63, wave = tid >> 6;
  const int g = lane >> 4, lr = lane & 15;
  char* wb = smem + 100352 + wave * 10368;  // per-wave scratch
  char* qb = wb;              // 3136
  char* kb = wb + 3136;       // 3136
  char* vt = wb + 6272;       // 4096
  char* pb = wb;              // P aliases qb+kb (6272) -- safe: in-order DS per wave

  const int bw = blockIdx.x;
  const float* xs = x + (size_t)bw * 25088;
  const float* ys = y + (size_t)bw * 25088;

  // ---- stage x,y windows to LDS as bf16 (coalesced float4 loads) ----
  for (int it = tid; it < 6272; it += 256) {
    float4 v = ((const float4*)xs)[it];
    float4 w = ((const float4*)ys)[it];
    int i = it >> 7;               // row 0..48
    int k = (it & 127) << 2;       // col 0..508
    unsigned a = ((unsigned)(i * 1024 + k * 2)) ^ (((unsigned)i & 7u) << 4);
    uint2 ux, uy;
    ux.x = (unsigned)f2bf(v.x) | ((unsigned)f2bf(v.y) << 16);
    ux.y = (unsigned)f2bf(v.z) | ((unsigned)f2bf(v.w) << 16);
    uy.x = (unsigned)f2bf(w.x) | ((unsigned)f2bf(w.y) << 16);
    uy.y = (unsigned)f2bf(w.z) | ((unsigned)f2bf(w.w) << 16);
    *(uint2*)(xb + a) = ux;
    *(uint2*)(yb + a) = uy;
  }
  __syncthreads();

  const bf16x8* wsQ = (const bf16x8*)wsW;
  const bf16x8* wsK = (const bf16x8*)(wsW + 524288);
  const bf16x8* wsV = (const bf16x8*)(wsW + 1048576);
  const f32x4* bD = (const f32x4*)biasD;
  const f32x4 fz = {0.f, 0.f, 0.f, 0.f};

  for (int hi = 0; hi < 4; ++hi) {
    const int h = wave * 4 + hi;

    // ---- Q = Xw @ Wq_h : 64x32 (4 M-tiles x 2 N-tiles), K=512 ----
    f32x4 accq[4][2];
    #pragma unroll
    for (int mt = 0; mt < 4; ++mt) { accq[mt][0] = fz; accq[mt][1] = fz; }
    #pragma unroll 4
    for (int ks = 0; ks < 16; ++ks) {
      int kc = ks * 32 + g * 8;
      bf16x8 a0 = ldXY(xb, lr, kc);
      bf16x8 a1 = ldXY(xb, lr + 16, kc);
      bf16x8 a2 = ldXY(xb, lr + 32, kc);
      bf16x8 a3 = ldXY_c(xb, lr + 48, kc);
      bf16x8 b0 = wsQ[((h * 2 + 0) * 16 + ks) * 64 + lane];
      bf16x8 b1 = wsQ[((h * 2 + 1) * 16 + ks) * 64 + lane];
      accq[0][0] = MFMA16(a0, b0, accq[0][0]);
      accq[1][0] = MFMA16(a1, b0, accq[1][0]);
      accq[2][0] = MFMA16(a2, b0, accq[2][0]);
      accq[3][0] = MFMA16(a3, b0, accq[3][0]);
      accq[0][1] = MFMA16(a0, b1, accq[0][1]);
      accq[1][1] = MFMA16(a1, b1, accq[1][1]);
      accq[2][1] = MFMA16(a2, b1, accq[2][1]);
      accq[3][1] = MFMA16(a3, b1, accq[3][1]);
    }
    // store q (D-layout -> [row][dh] bf16 in qb)
    #pragma unroll
    for (int mt = 0; mt < 4; ++mt)
      #pragma unroll
      for (int nt = 0; nt < 2; ++nt)
        #pragma unroll
        for (int r = 0; r < 4; ++r) {
          int row = mt * 16 + g * 4 + r;
          if (row < 49) {
            unsigned a = ((unsigned)(row * 64 + (nt * 16 + lr) * 2)) ^ (((unsigned)row & 3u) << 4);
            *(unsigned short*)(qb + a) = f2bf(accq[mt][nt][r]);
          }
        }

    // ---- K,V = Yw @ Wk_h / Wv_h (shared A-frags) ----
    f32x4 acck[4][2], accv[4][2];
    #pragma unroll
    for (int mt = 0; mt < 4; ++mt) {
      acck[mt][0] = fz; acck[mt][1] = fz; accv[mt][0] = fz; accv[mt][1] = fz;
    }
    #pragma unroll 4
    for (int ks = 0; ks < 16; ++ks) {
      int kc = ks * 32 + g * 8;
      bf16x8 a0 = ldXY(yb, lr, kc);
      bf16x8 a1 = ldXY(yb, lr + 16, kc);
      bf16x8 a2 = ldXY(yb, lr + 32, kc);
      bf16x8 a3 = ldXY_c(yb, lr + 48, kc);
      bf16x8 bk0 = wsK[((h * 2 + 0) * 16 + ks) * 64 + lane];
      bf16x8 bk1 = wsK[((h * 2 + 1) * 16 + ks) * 64 + lane];
      bf16x8 bv0 = wsV[((h * 2 + 0) * 16 + ks) * 64 + lane];
      bf16x8 bv1 = wsV[((h * 2 + 1) * 16 + ks) * 64 + lane];
      acck[0][0] = MFMA16(a0, bk0, acck[0][0]);
      acck[1][0] = MFMA16(a1, bk0, acck[1][0]);
      acck[2][0] = MFMA16(a2, bk0, acck[2][0]);
      acck[3][0] = MFMA16(a3, bk0, acck[3][0]);
      acck[0][1] = MFMA16(a0, bk1, acck[0][1]);
      acck[1][1] = MFMA16(a1, bk1, acck[1][1]);
      acck[2][1] = MFMA16(a2, bk1, acck[2][1]);
      acck[3][1] = MFMA16(a3, bk1, acck[3][1]);
      accv[0][0] = MFMA16(a0, bv0, accv[0][0]);
      accv[1][0] = MFMA16(a1, bv0, accv[1][0]);
      accv[2][0] = MFMA16(a2, bv0, accv[2][0]);
      accv[3][0] = MFMA16(a3, bv0, accv[3][0]);
      accv[0][1] = MFMA16(a0, bv1, accv[0][1]);
      accv[1][1] = MFMA16(a1, bv1, accv[1][1]);
      accv[2][1] = MFMA16(a2, bv1, accv[2][1]);
      accv[3][1] = MFMA16(a3, bv1, accv[3][1]);
    }
    // store k ([row][dh]) and v transposed ([dh][j]; padded j rows are 0 already)
    #pragma unroll
    for (int mt = 0; mt < 4; ++mt)
      #pragma unroll
      for (int nt = 0; nt < 2; ++nt)
        #pragma unroll
        for (int r = 0; r < 4; ++r) {
          int row = mt * 16 + g * 4 + r;
          int dh = nt * 16 + lr;
          if (row < 49) {
            unsigned a = ((unsigned)(row * 64 + dh * 2)) ^ (((unsigned)row & 3u) << 4);
            *(unsigned short*)(kb + a) = f2bf(acck[mt][nt][r]);
          }
          unsigned av = ((unsigned)(dh * 128 + row * 2)) ^ (((unsigned)dh & 7u) << 4);
          *(unsigned short*)(vt + av) = f2bf(accv[mt][nt][r]);
        }

    // ---- sim = q @ k^T (both operands read in identical [row][32] form) ----
    bf16x8 qa[4], kf[4];
    #pragma unroll
    for (int t2 = 0; t2 < 4; ++t2) {
      qa[t2] = ldQK(qb, lr + t2 * 16, g * 8);
      kf[t2] = ldQK(kb, lr + t2 * 16, g * 8);
    }
    f32x4 accs[4][4];
    #pragma unroll
    for (int mt = 0; mt < 4; ++mt)
      #pragma unroll
      for (int nt = 0; nt < 4; ++nt)
        accs[mt][nt] = MFMA16(qa[mt], kf[nt], fz);

    // ---- bias + softmax (row-parallel via 16-lane butterflies) ----
    float ssum[4][4];
    #pragma unroll
    for (int mt = 0; mt < 4; ++mt) {
      f32x4 vals[4];
      #pragma unroll
      for (int nt = 0; nt < 4; ++nt)
        vals[nt] = accs[mt][nt] + bD[((h * 4 + mt) * 4 + nt) * 64 + lane];
      #pragma unroll
      for (int r = 0; r < 4; ++r) {
        float m = fmaxf(fmaxf(vals[0][r], vals[1][r]), fmaxf(vals[2][r], vals[3][r]));
        m = fmaxf(m, __shfl_xor(m, 1));
        m = fmaxf(m, __shfl_xor(m, 2));
        m = fmaxf(m, __shfl_xor(m, 4));
        m = fmaxf(m, __shfl_xor(m, 8));
        float s = 0.f;
        #pragma unroll
        for (int nt = 0; nt < 4; ++nt) {
          float p = __expf(vals[nt][r] - m);
          vals[nt][r] = p;
          s += p;
        }
        s += __shfl_xor(s, 1);
        s += __shfl_xor(s, 2);
        s += __shfl_xor(s, 4);
        s += __shfl_xor(s, 8);
        ssum[mt][r] = s;
      }
      // write P (unnormalized exp) as bf16 to pb
      #pragma unroll
      for (int r = 0; r < 4; ++r) {
        int row = mt * 16 + g * 4 + r;
        if (row < 49) {
          #pragma unroll
          for (int nt = 0; nt < 4; ++nt) {
            unsigned a = ((unsigned)(row * 128 + (nt * 16 + lr) * 2)) ^ (((unsigned)row & 7u) << 4);
            *(unsigned short*)(pb + a) = f2bf(vals[nt][r]);
          }
        }
      }
    }

    // ---- out = P @ V (V read from transposed vt: contiguous b128 B-frags) ----
    f32x4 acco[4][2];
    #pragma unroll
    for (int mt = 0; mt < 4; ++mt) { acco[mt][0] = fz; acco[mt][1] = fz; }
    #pragma unroll
    for (int ks = 0; ks < 2; ++ks) {
      int kc = ks * 32 + g * 8;
      bf16x8 p0 = ldP(pb, lr, kc);
      bf16x8 p1 = ldP(pb, lr + 16, kc);
      bf16x8 p2 = ldP(pb, lr + 32, kc);
      bf16x8 p3 = ldP(pb, lr + 48, kc);
      bf16x8 v0 = ldVT(vt, lr, kc);
      bf16x8 v1 = ldVT(vt, lr + 16, kc);
      acco[0][0] = MFMA16(p0, v0, acco[0][0]);
      acco[1][0] = MFMA16(p1, v0, acco[1][0]);
      acco[2][0] = MFMA16(p2, v0, acco[2][0]);
      acco[3][0] = MFMA16(p3, v0, acco[3][0]);
      acco[0][1] = MFMA16(p0, v1, acco[0][1]);
      acco[1][1] = MFMA16(p1, v1, acco[1][1]);
      acco[2][1] = MFMA16(p2, v1, acco[2][1]);
      acco[3][1] = MFMA16(p3, v1, acco[3][1]);
    }

    // ---- normalize + store ----
    float* ow = out + (size_t)bw * 25088 + h * 32;
    #pragma unroll
    for (int mt = 0; mt < 4; ++mt)
      #pragma unroll
      for (int r = 0; r < 4; ++r) {
        int row = mt * 16 + g * 4 + r;
        if (row < 49) {
          float inv = 1.0f / ssum[mt][r];
          ow[row * 512 + lr] = acco[mt][0][r] * inv;
          ow[row * 512 + 16 + lr] = acco[mt][1][r] * inv;
        }
      }
  }
}

extern "C" void kernel_launch(void* const* d_in, const int* in_sizes, int n_in,
                              void* d_out, int out_size, void* d_ws, size_t ws_size,
                              hipStream_t stream) {
  (void)in_sizes; (void)n_in; (void)out_size; (void)ws_size;
  const float* x = (const float*)d_in[0];
  const float* y = (const float*)d_in[1];
  const float* Wq = (const float*)d_in[2];
  const float* Wkv = (const float*)d_in[3];
  const float* bt = (const float*)d_in[4];
  float* out = (float*)d_out;
  char* ws = (char*)d_ws;

  prep_kernel<<<3072, 256, 0, stream>>>(Wq, Wkv, bt, ws);

  (void)hipFuncSetAttribute((const void*)attn_kernel,
                            hipFuncAttributeMaxDynamicSharedMemorySize, 141824);
  attn_kernel<<<4096, 256, 141824, stream>>>(x, y, (const char*)ws,
                                             (const float*)(ws + 1572864), out);
}

// Round 2
// 932.675 us; speedup vs baseline: 1.2743x; 1.2743x over previous
//
#include <hip/hip_runtime.h>

// ---------------------------------------------------------------------------
// Grid attention, fused per-window kernel v2, bf16 MFMA (gfx950).
//   4096 windows; n=49 tokens; D=512; 16 heads x 32.
//   512 threads = 8 waves = 2 waves/SIMD. Wave pairs share scratch:
//   pair p handles heads p*4..p*4+3; within a head, sub-wave 0/1 split
//   N (projections) and M (QK/softmax) / tok (PV).
// ws layout (2.5MB):
//   [0, 512KB)        Wq  pre-swizzled B-frags  [h][nt][ks][lane][8] bf16 (scale folded)
//   [512KB, 1MB)      Wk  same
//   [1MB, 1.5MB)      Wv  same
//   [1.5MB, 2.5MB)    biasD [h][mt][nt][lane][4] f32 (D-layout; -1e30 for j>=49)
// ---------------------------------------------------------------------------

typedef __bf16 bf16x8 __attribute__((ext_vector_type(8)));
typedef __attribute__((ext_vector_type(8))) short short8;
typedef __attribute__((ext_vector_type(4))) float f32x4;

#define DEVI __device__ __forceinline__

DEVI unsigned short f2bf(float f) {
  union { float f; unsigned u; } v; v.f = f;
  unsigned r = v.u + 0x7FFFu + ((v.u >> 16) & 1u);
  return (unsigned short)(r >> 16);
}

DEVI bf16x8 bf_zero() {
  short8 z = {0, 0, 0, 0, 0, 0, 0, 0};
  return __builtin_bit_cast(bf16x8, z);
}

#define MFMA16(a, b, c) __builtin_amdgcn_mfma_f32_16x16x32_bf16((a), (b), (c), 0, 0, 0)

// ---------------- prep: weights -> swizzled bf16 frags, bias -> D-layout ----
__global__ void prep_kernel(const float* __restrict__ Wq, const float* __restrict__ Wkv,
                            const float* __restrict__ bt, char* __restrict__ ws) {
  int t = blockIdx.x * 256 + threadIdx.x;
  if (t < 786432) {  // 3 * 16 * 2 * 16 * 64 * 8 bf16 elements
    int e = t & 7, lane = (t >> 3) & 63, ks = (t >> 9) & 15, nt = (t >> 13) & 1,
        h = (t >> 14) & 15, T = t >> 18;
    int row = ks * 32 + (lane >> 4) * 8 + e;     // K index in [0,512)
    int col = h * 32 + nt * 16 + (lane & 15);    // N index
    float v;
    if (T == 0)      v = Wq[row * 512 + col] * 0.17677669529663687f;  // fold 1/sqrt(32)
    else if (T == 1) v = Wkv[row * 1024 + col];
    else             v = Wkv[row * 1024 + 512 + col];
    ((unsigned short*)ws)[t] = f2bf(v);
  }
  if (t < 262144) {  // 16 * 4 * 4 * 64 * 4 f32
    int r = t & 3, lane = (t >> 2) & 63, nt = (t >> 8) & 3, mt = (t >> 10) & 3,
        h = (t >> 12) & 15;
    int i = mt * 16 + (lane >> 4) * 4 + r;
    int j = nt * 16 + (lane & 15);
    float v;
    if (j >= 49)      v = -1e30f;   // mask padded key columns
    else if (i >= 49) v = 0.0f;     // padded query rows: keep finite
    else {
      int hi = i / 7, wi = i % 7, hj = j / 7, wj = j % 7;
      v = bt[((hi - hj + 6) * 13 + (wi - wj + 6)) * 16 + h];
    }
    ((float*)(ws + 1572864))[t] = v;
  }
}

// ---------------- LDS fragment loaders (XOR-swizzled) -----------------------
// xb/yb: [49][512] bf16, row stride 1024B, swz bits 4-6
DEVI bf16x8 ldXY(const char* base, int row, int kc) {
  unsigned a = ((unsigned)(row * 1024 + kc * 2)) ^ (((unsigned)row & 7u) << 4);
  return *(const bf16x8*)(base + a);
}
DEVI bf16x8 ldXY_c(const char* base, int row, int kc) {
  int rc = row < 48 ? row : 48;
  bf16x8 v = ldXY(base, rc, kc);
  if (row > 48) v = bf_zero();
  return v;
}
// qb/kb: [49][32] bf16, row stride 64B, swz bits 4-5
DEVI bf16x8 ldQK(const char* base, int row, int kc) {
  int rc = row < 48 ? row : 48;
  unsigned a = ((unsigned)(rc * 64 + kc * 2)) ^ (((unsigned)rc & 3u) << 4);
  bf16x8 v = *(const bf16x8*)(base + a);
  if (row > 48) v = bf_zero();
  return v;
}
// pb: [49][64] bf16, row stride 128B, swz bits 4-6
DEVI bf16x8 ldP(const char* base, int row, int kc) {
  int rc = row < 48 ? row : 48;
  unsigned a = ((unsigned)(rc * 128 + kc * 2)) ^ (((unsigned)rc & 7u) << 4);
  bf16x8 v = *(const bf16x8*)(base + a);
  if (row > 48) v = bf_zero();
  return v;
}
// vt: [32][64] bf16 (V transposed: [dh][tok]), row stride 128B, swz bits 4-6
DEVI bf16x8 ldVT(const char* base, int dh, int kc) {
  unsigned a = ((unsigned)(dh * 128 + kc * 2)) ^ (((unsigned)dh & 7u) << 4);
  return *(const bf16x8*)(base + a);
}

// ---------------- main fused kernel ----------------------------------------
__global__ __launch_bounds__(512, 2)
void attn_kernel(const float* __restrict__ x, const float* __restrict__ y,
                 const char* __restrict__ wsW, const float* __restrict__ biasD,
                 float* __restrict__ out) {
  extern __shared__ char smem[];
  char* xb = smem;            // 50176
  char* yb = smem + 50176;    // 50176
  const int tid = threadIdx.x;
  const int lane = tid & 63, wave = tid >> 6;
  const int p = wave >> 1, sub = wave & 1;
  const int g = lane >> 4, lr = lane & 15;
  char* wb = smem + 100352 + p * 10624;  // per-PAIR scratch
  char* qb = wb;              // 3136
  char* kb = wb + 3136;       // 3136
  char* vt = wb + 6272;       // 4096
  char* pb = wb;              // P aliases qb+kb (6272 bytes: rows 0..48 x 128B)
  float* sb = (float*)(wb + 10368);  // 64 inv-sums

  const int bw = blockIdx.x;
  const float* xs = x + (size_t)bw * 25088;
  const float* ys = y + (size_t)bw * 25088;

  // ---- stage x,y windows to LDS as bf16 ----
  for (int it = tid; it < 6272; it += 512) {
    float4 v = ((const float4*)xs)[it];
    float4 w = ((const float4*)ys)[it];
    int i = it >> 7;               // row 0..48
    int k = (it & 127) << 2;       // col 0..508
    unsigned a = ((unsigned)(i * 1024 + k * 2)) ^ (((unsigned)i & 7u) << 4);
    uint2 ux, uy;
    ux.x = (unsigned)f2bf(v.x) | ((unsigned)f2bf(v.y) << 16);
    ux.y = (unsigned)f2bf(v.z) | ((unsigned)f2bf(v.w) << 16);
    uy.x = (unsigned)f2bf(w.x) | ((unsigned)f2bf(w.y) << 16);
    uy.y = (unsigned)f2bf(w.z) | ((unsigned)f2bf(w.w) << 16);
    *(uint2*)(xb + a) = ux;
    *(uint2*)(yb + a) = uy;
  }

  const bf16x8* wsQ = (const bf16x8*)wsW;
  const bf16x8* wsK = (const bf16x8*)(wsW + 524288);
  const bf16x8* wsV = (const bf16x8*)(wsW + 1048576);
  const f32x4* bD = (const f32x4*)biasD;
  const f32x4 fz = {0.f, 0.f, 0.f, 0.f};

  for (int hi = 0; hi < 4; ++hi) {
    const int h = p * 4 + hi;

    __syncthreads();  // scratch safe to rewrite (partner's PV of prev head done)

    // ---- Q = Xw @ Wq_h, N-split: this wave computes cols sub*16..+16 ----
    f32x4 accq[4];
    #pragma unroll
    for (int mt = 0; mt < 4; ++mt) accq[mt] = fz;
    {
      const bf16x8* pQ = wsQ + (size_t)((h * 2 + sub) * 16) * 64 + lane;
      bf16x8 bq = pQ[0];
      #pragma unroll 4
      for (int ks = 0; ks < 16; ++ks) {
        bf16x8 bn = (ks < 15) ? pQ[(ks + 1) * 64] : bq;  // prefetch next B-frag
        int kc = ks * 32 + g * 8;
        bf16x8 a0 = ldXY(xb, lr, kc);
        bf16x8 a1 = ldXY(xb, lr + 16, kc);
        bf16x8 a2 = ldXY(xb, lr + 32, kc);
        bf16x8 a3 = ldXY_c(xb, lr + 48, kc);
        accq[0] = MFMA16(a0, bq, accq[0]);
        accq[1] = MFMA16(a1, bq, accq[1]);
        accq[2] = MFMA16(a2, bq, accq[2]);
        accq[3] = MFMA16(a3, bq, accq[3]);
        bq = bn;
      }
    }
    // store q (D-layout -> [row][dh] bf16), dh = sub*16 + lr
    #pragma unroll
    for (int mt = 0; mt < 4; ++mt)
      #pragma unroll
      for (int r = 0; r < 4; ++r) {
        int row = mt * 16 + g * 4 + r;
        if (row < 49) {
          unsigned a = ((unsigned)(row * 64 + (sub * 16 + lr) * 2)) ^ (((unsigned)row & 3u) << 4);
          *(unsigned short*)(qb + a) = f2bf(accq[mt][r]);
        }
      }

    // ---- K,V = Yw @ Wk_h / Wv_h, N-split ----
    f32x4 acck[4], accv[4];
    #pragma unroll
    for (int mt = 0; mt < 4; ++mt) { acck[mt] = fz; accv[mt] = fz; }
    {
      const bf16x8* pK = wsK + (size_t)((h * 2 + sub) * 16) * 64 + lane;
      const bf16x8* pV = wsV + (size_t)((h * 2 + sub) * 16) * 64 + lane;
      bf16x8 bk = pK[0], bv = pV[0];
      #pragma unroll 4
      for (int ks = 0; ks < 16; ++ks) {
        bf16x8 bk2 = (ks < 15) ? pK[(ks + 1) * 64] : bk;
        bf16x8 bv2 = (ks < 15) ? pV[(ks + 1) * 64] : bv;
        int kc = ks * 32 + g * 8;
        bf16x8 a0 = ldXY(yb, lr, kc);
        bf16x8 a1 = ldXY(yb, lr + 16, kc);
        bf16x8 a2 = ldXY(yb, lr + 32, kc);
        bf16x8 a3 = ldXY_c(yb, lr + 48, kc);
        acck[0] = MFMA16(a0, bk, acck[0]);
        acck[1] = MFMA16(a1, bk, acck[1]);
        acck[2] = MFMA16(a2, bk, acck[2]);
        acck[3] = MFMA16(a3, bk, acck[3]);
        accv[0] = MFMA16(a0, bv, accv[0]);
        accv[1] = MFMA16(a1, bv, accv[1]);
        accv[2] = MFMA16(a2, bv, accv[2]);
        accv[3] = MFMA16(a3, bv, accv[3]);
        bk = bk2; bv = bv2;
      }
    }
    // store k ([row][dh], scatter u16) and v transposed ([dh][tok], packed b64)
    #pragma unroll
    for (int mt = 0; mt < 4; ++mt) {
      #pragma unroll
      for (int r = 0; r < 4; ++r) {
        int row = mt * 16 + g * 4 + r;
        if (row < 49) {
          unsigned a = ((unsigned)(row * 64 + (sub * 16 + lr) * 2)) ^ (((unsigned)row & 3u) << 4);
          *(unsigned short*)(kb + a) = f2bf(acck[mt][r]);
        }
      }
      int dh = sub * 16 + lr;
      int t0 = mt * 16 + g * 4;
      unsigned av = ((unsigned)(dh * 128 + t0 * 2)) ^ (((unsigned)dh & 7u) << 4);
      uint2 pk;
      pk.x = (unsigned)f2bf(accv[mt][0]) | ((unsigned)f2bf(accv[mt][1]) << 16);
      pk.y = (unsigned)f2bf(accv[mt][2]) | ((unsigned)f2bf(accv[mt][3]) << 16);
      *(uint2*)(vt + av) = pk;
    }

    __syncthreads();  // q,k,v visible to both waves of the pair

    // ---- sim = q @ k^T, M-split: this wave does rows sub*32..+32 ----
    bf16x8 qa[2], kf[4];
    #pragma unroll
    for (int mi = 0; mi < 2; ++mi) qa[mi] = ldQK(qb, sub * 32 + mi * 16 + lr, g * 8);
    #pragma unroll
    for (int nt = 0; nt < 4; ++nt) kf[nt] = ldQK(kb, nt * 16 + lr, g * 8);
    f32x4 accs[2][4];
    #pragma unroll
    for (int mi = 0; mi < 2; ++mi)
      #pragma unroll
      for (int nt = 0; nt < 4; ++nt)
        accs[mi][nt] = MFMA16(qa[mi], kf[nt], fz);

    // ---- bias + softmax (16-lane butterflies), rows sub*32..+32 ----
    float sinv[2][4];
    #pragma unroll
    for (int mi = 0; mi < 2; ++mi) {
      int mt_g = sub * 2 + mi;
      f32x4 vals[4];
      #pragma unroll
      for (int nt = 0; nt < 4; ++nt)
        vals[nt] = accs[mi][nt] + bD[((h * 4 + mt_g) * 4 + nt) * 64 + lane];
      #pragma unroll
      for (int r = 0; r < 4; ++r) {
        float m = fmaxf(fmaxf(vals[0][r], vals[1][r]), fmaxf(vals[2][r], vals[3][r]));
        m = fmaxf(m, __shfl_xor(m, 1));
        m = fmaxf(m, __shfl_xor(m, 2));
        m = fmaxf(m, __shfl_xor(m, 4));
        m = fmaxf(m, __shfl_xor(m, 8));
        float s = 0.f;
        #pragma unroll
        for (int nt = 0; nt < 4; ++nt) {
          float pv = __expf(vals[nt][r] - m);
          vals[nt][r] = pv;
          s += pv;
        }
        s += __shfl_xor(s, 1);
        s += __shfl_xor(s, 2);
        s += __shfl_xor(s, 4);
        s += __shfl_xor(s, 8);
        sinv[mi][r] = 1.0f / s;
      }
      accs[mi][0] = vals[0]; accs[mi][1] = vals[1];
      accs[mi][2] = vals[2]; accs[mi][3] = vals[3];
    }

    __syncthreads();  // both waves done reading qb/kb frags -> pb may overwrite

    // ---- write P (unnormalized) + inv-sums ----
    #pragma unroll
    for (int mi = 0; mi < 2; ++mi) {
      int mt_g = sub * 2 + mi;
      #pragma unroll
      for (int r = 0; r < 4; ++r) {
        int row = mt_g * 16 + g * 4 + r;
        if (row < 49) {
          #pragma unroll
          for (int nt = 0; nt < 4; ++nt) {
            unsigned a = ((unsigned)(row * 128 + (nt * 16 + lr) * 2)) ^ (((unsigned)row & 7u) << 4);
            *(unsigned short*)(pb + a) = f2bf(accs[mi][nt][r]);
          }
          if (lr == 0) sb[row] = sinv[mi][r];
        }
      }
    }

    // ---- PV, swapped operands: out^T[dh][tok] = V^T @ P^T-shaped ----
    // A-frag = vt rows dh (both halves, written pre-barrier); B-frag = own P rows.
    f32x4 acco[2][2];
    acco[0][0] = fz; acco[0][1] = fz; acco[1][0] = fz; acco[1][1] = fz;
    #pragma unroll
    for (int ks = 0; ks < 2; ++ks) {
      int jc = ks * 32 + g * 8;
      bf16x8 av0 = ldVT(vt, lr, jc);
      bf16x8 av1 = ldVT(vt, lr + 16, jc);
      bf16x8 bp0 = ldP(pb, (sub * 2 + 0) * 16 + lr, jc);
      bf16x8 bp1 = ldP(pb, (sub * 2 + 1) * 16 + lr, jc);
      acco[0][0] = MFMA16(av0, bp0, acco[0][0]);
      acco[0][1] = MFMA16(av0, bp1, acco[0][1]);
      acco[1][0] = MFMA16(av1, bp0, acco[1][0]);
      acco[1][1] = MFMA16(av1, bp1, acco[1][1]);
    }

    // ---- normalize + store (float4, dh-contiguous) ----
    float* ow = out + (size_t)bw * 25088 + h * 32;
    #pragma unroll
    for (int ntl = 0; ntl < 2; ++ntl) {
      int tok = (sub * 2 + ntl) * 16 + lr;
      if (tok < 49) {
        float inv = sb[tok];
        #pragma unroll
        for (int mt = 0; mt < 2; ++mt) {
          f32x4 vv = acco[mt][ntl];
          vv[0] *= inv; vv[1] *= inv; vv[2] *= inv; vv[3] *= inv;
          *(f32x4*)(&ow[(size_t)tok * 512 + mt * 16 + g * 4]) = vv;
        }
      }
    }
  }
}

extern "C" void kernel_launch(void* const* d_in, const int* in_sizes, int n_in,
                              void* d_out, int out_size, void* d_ws, size_t ws_size,
                              hipStream_t stream) {
  (void)in_sizes; (void)n_in; (void)out_size; (void)ws_size;
  const float* x = (const float*)d_in[0];
  const float* y = (const float*)d_in[1];
  const float* Wq = (const float*)d_in[2];
  const float* Wkv = (const float*)d_in[3];
  const float* bt = (const float*)d_in[4];
  float* out = (float*)d_out;
  char* ws = (char*)d_ws;

  prep_kernel<<<3072, 256, 0, stream>>>(Wq, Wkv, bt, ws);

  (void)hipFuncSetAttribute((const void*)attn_kernel,
                            hipFuncAttributeMaxDynamicSharedMemorySize, 142848);
  attn_kernel<<<4096, 512, 142848, stream>>>(x, y, (const char*)ws,
                                             (const float*)(ws + 1572864), out);
}